// Round 4
// baseline (591.652 us; speedup 1.0000x reference)
//
#include <hip/hip_runtime.h>
#include <hip/hip_bf16.h>
#include <math.h>

#define N_NODESC 32768
#define N_EDGESC 524288
#define NPG 8192
#define KOUT 512

typedef unsigned short u16;
typedef unsigned int u32;

__device__ __forceinline__ float siluf(float x) {
    return x / (1.f + expf(-x));
}

// ---------------- zero deg ----------------
__global__ __launch_bounds__(256) void k_zero(int* deg) {
    int i = blockIdx.x * 256 + threadIdx.x;
    if (i < N_NODESC) deg[i] = 0;
}

// ---------------- h0 = x@proj_w + proj_b + sincos(mesh_pos) ----------------
__global__ __launch_bounds__(256) void k_h0(const float* __restrict__ x,
                                            const float* __restrict__ pos,
                                            const float* __restrict__ pw,
                                            const float* __restrict__ pb,
                                            float* __restrict__ h) {
    int node = blockIdx.x * 2 + (threadIdx.x >> 7);
    int c = threadIdx.x & 127;
    float x0 = x[node * 3 + 0];
    float x1 = x[node * 3 + 1];
    float x2 = x[node * 3 + 2];
    float acc = x0 * pw[c] + x1 * pw[128 + c] + x2 * pw[256 + c];
    acc += pb[c];
    int dim = c >> 6;          // which pos coordinate
    int inner = c & 63;        // 0..63 within [sin(32), cos(32)]
    int jj = inner & 31;
    float p = pos[node * 2 + dim];
    // omega_j = 10000^(-j/32); log2(10000)/32 computed in double for accuracy
    float omega = (float)exp2(-(double)jj * (13.287712379549449 / 32.0));
    float ang = p * omega;
    acc += (inner < 32) ? sinf(ang) : cosf(ang);
    h[(size_t)node * 128 + c] = acc;
}

// ---------------- degree histogram ----------------
__global__ __launch_bounds__(256) void k_deg(const int* __restrict__ edges, int* __restrict__ deg) {
    int e = blockIdx.x * 256 + threadIdx.x;
    if (e < N_EDGESC) atomicAdd(&deg[edges[2 * e + 1]], 1);
}

// ---------------- exclusive scan (32768 = 1024 threads x 32) ----------------
__global__ __launch_bounds__(1024) void k_scan(const int* __restrict__ deg,
                                               int* __restrict__ off, int* __restrict__ cur,
                                               float* __restrict__ rs, float* __restrict__ bg) {
    __shared__ int ls[1024];
    int tid = threadIdx.x;
    int base = tid * 32;
    int v[32];
    int s = 0;
#pragma unroll
    for (int j = 0; j < 32; j++) { v[j] = deg[base + j]; s += v[j]; }
    ls[tid] = s;
    __syncthreads();
    for (int ofs = 1; ofs < 1024; ofs <<= 1) {
        int t = (tid >= ofs) ? ls[tid - ofs] : 0;
        __syncthreads();
        ls[tid] += t;
        __syncthreads();
    }
    int run = ls[tid] - s;  // exclusive prefix for this thread's chunk
#pragma unroll
    for (int j = 0; j < 32; j++) {
        off[base + j] = run;
        cur[base + j] = run;
        int d = v[j];
        rs[base + j] = 1.f / (float)(d > 0 ? d : 1);
        bg[base + j] = d > 0 ? 1.f : 0.f;
        run += d;
    }
}

// ---------------- CSR fill ----------------
__global__ __launch_bounds__(256) void k_fill(const int* __restrict__ edges,
                                              int* __restrict__ cur, int* __restrict__ csr) {
    int e = blockIdx.x * 256 + threadIdx.x;
    if (e < N_EDGESC) {
        int d = edges[2 * e + 1];
        int s = edges[2 * e + 0];
        int pos = atomicAdd(&cur[d], 1);
        csr[pos] = s;
    }
}

// ---------------- generic f32 GEMM: C = act((A1@W1 [+A2@W2])*rs + bias*bg + resid) ----------------
// A: [32768 x 128] f32, W: [128 x 128] f32 (row-major), C: [32768 x 128] f32
__global__ __launch_bounds__(256) void gemm128(const float* __restrict__ A1, const float* __restrict__ W1,
                                               const float* __restrict__ A2, const float* __restrict__ W2,
                                               const float* __restrict__ bias,
                                               const float* __restrict__ rs, const float* __restrict__ bg,
                                               const float* __restrict__ resid,
                                               float* __restrict__ C, int act) {
    int cg = threadIdx.x & 31;   // 32 col groups x 4 cols
    int rg = threadIdx.x >> 5;   // 8 row groups x 8 rows
    int m0 = blockIdx.x * 64 + rg * 8;
    int c0 = cg * 4;
    float acc[8][4];
#pragma unroll
    for (int r = 0; r < 8; r++)
#pragma unroll
        for (int c = 0; c < 4; c++) acc[r][c] = 0.f;

    const float* Arow1 = A1 + (size_t)m0 * 128;
    const float* Arow2 = A2 ? (A2 + (size_t)m0 * 128) : nullptr;

    for (int k0 = 0; k0 < 128; k0 += 4) {
        float4 a1[8];
#pragma unroll
        for (int r = 0; r < 8; r++) a1[r] = *(const float4*)(Arow1 + r * 128 + k0);
#pragma unroll
        for (int kk = 0; kk < 4; kk++) {
            float4 w = *(const float4*)(W1 + (size_t)(k0 + kk) * 128 + c0);
#pragma unroll
            for (int r = 0; r < 8; r++) {
                float a = ((const float*)&a1[r])[kk];
                acc[r][0] += a * w.x;
                acc[r][1] += a * w.y;
                acc[r][2] += a * w.z;
                acc[r][3] += a * w.w;
            }
        }
        if (A2) {
            float4 a2[8];
#pragma unroll
            for (int r = 0; r < 8; r++) a2[r] = *(const float4*)(Arow2 + r * 128 + k0);
#pragma unroll
            for (int kk = 0; kk < 4; kk++) {
                float4 w = *(const float4*)(W2 + (size_t)(k0 + kk) * 128 + c0);
#pragma unroll
                for (int r = 0; r < 8; r++) {
                    float a = ((const float*)&a2[r])[kk];
                    acc[r][0] += a * w.x;
                    acc[r][1] += a * w.y;
                    acc[r][2] += a * w.z;
                    acc[r][3] += a * w.w;
                }
            }
        }
    }

#pragma unroll
    for (int r = 0; r < 8; r++) {
        int row = m0 + r;
        float rsv = rs ? rs[row] : 1.f;
        float bgv = bg ? bg[row] : 1.f;
        float4 o;
        float* op = (float*)&o;
#pragma unroll
        for (int c = 0; c < 4; c++) {
            float xv = acc[r][c] * rsv;
            if (bias) xv += bias[c0 + c] * bgv;
            if (resid) xv += resid[(size_t)row * 128 + c0 + c];
            if (act) xv = siluf(xv);
            op[c] = xv;
        }
        *(float4*)(C + (size_t)row * 128 + c0) = o;
    }
}

// ---------------- S[d] = sum_{e:dst=d} silu(u[d] + v[src_e]) ; wave per node ----------------
// u[d] computed on the fly: u[d][c] = b1[c] + sum_k h[d][k]*W1a[k][c]
__global__ __launch_bounds__(256) void k_accum_S(const float* __restrict__ h,
                                                 const float* __restrict__ w1a,
                                                 const float* __restrict__ b1,
                                                 const float* __restrict__ v,
                                                 const int* __restrict__ csr, const int* __restrict__ off,
                                                 const int* __restrict__ deg, float* __restrict__ S) {
    int d = blockIdx.x * 4 + (threadIdx.x >> 6);
    int lane = threadIdx.x & 63;
    // u row on the fly (weights are L1/L2-resident: 64KB, reused by all waves)
    float u0 = b1[lane];
    float u1 = b1[64 + lane];
    const float* hrow = h + (size_t)d * 128;
    for (int k = 0; k < 128; k++) {
        float hk = hrow[k];
        u0 += hk * w1a[(size_t)k * 128 + lane];
        u1 += hk * w1a[(size_t)k * 128 + 64 + lane];
    }
    float a0 = 0.f, a1 = 0.f;
    int o = off[d], n = deg[d];
    for (int j = 0; j < n; j++) {
        int s = csr[o + j];
        float v0 = v[(size_t)s * 128 + lane];
        float v1 = v[(size_t)s * 128 + 64 + lane];
        a0 += siluf(u0 + v0);
        a1 += siluf(u1 + v1);
    }
    S[(size_t)d * 128 + lane] = a0;
    S[(size_t)d * 128 + 64 + lane] = a1;
}

// ---------------- p = h.pool_rel_w, r = h.pool_root_w ; wave per node ----------------
__global__ __launch_bounds__(256) void k_pr(const float* __restrict__ h,
                                            const float* __restrict__ wrel, const float* __restrict__ wroot,
                                            float* __restrict__ p, float* __restrict__ r) {
    int d = blockIdx.x * 4 + (threadIdx.x >> 6);
    int lane = threadIdx.x & 63;
    float h0 = h[(size_t)d * 128 + lane];
    float h1 = h[(size_t)d * 128 + 64 + lane];
    float prel = h0 * wrel[lane] + h1 * wrel[64 + lane];
    float proot = h0 * wroot[lane] + h1 * wroot[64 + lane];
    for (int m = 32; m > 0; m >>= 1) {
        prel += __shfl_xor(prel, m);
        proot += __shfl_xor(proot, m);
    }
    if (lane == 0) { p[d] = prel; r[d] = proot; }
}

// ---------------- score[d] = tanh( (sum p[src]) / cnt + rel_b + r[d] ) ----------------
__global__ __launch_bounds__(256) void k_score(const float* __restrict__ p, const float* __restrict__ r,
                                               const int* __restrict__ csr, const int* __restrict__ off,
                                               const int* __restrict__ deg, const float* __restrict__ relb,
                                               float* __restrict__ score) {
    int d = blockIdx.x * 4 + (threadIdx.x >> 6);
    int lane = threadIdx.x & 63;
    int o = off[d], n = deg[d];
    float a = 0.f;
    for (int j = lane; j < n; j += 64) a += p[csr[o + j]];
    for (int m = 32; m > 0; m >>= 1) a += __shfl_xor(a, m);
    if (lane == 0) {
        float cnt = (float)(n > 0 ? n : 1);
        score[d] = tanhf(a / cnt + relb[0] + r[d]);
    }
}

// ---------------- per-graph bitonic top-k + output write (FLOAT32 out) ----------------
__global__ __launch_bounds__(1024) void k_topk(const float* __restrict__ score, const float* __restrict__ h,
                                               float* __restrict__ out) {
    __shared__ float sv[NPG];
    __shared__ u16 si[NPG];
    int g = blockIdx.x;
    int tid = threadIdx.x;
    for (int i = tid; i < NPG; i += 1024) {
        sv[i] = score[(size_t)g * NPG + i];
        si[i] = (u16)i;
    }
    for (int k = 2; k <= NPG; k <<= 1) {
        for (int j = k >> 1; j > 0; j >>= 1) {
            __syncthreads();
            for (int t = tid; t < NPG / 2; t += 1024) {
                int i = ((t & ~(j - 1)) << 1) | (t & (j - 1));
                int pr = i | j;
                float vi = sv[i], vp = sv[pr];
                int ii = si[i], ip = si[pr];
                // gt(a,b): a ranks before b in final order (desc value, tie -> lower idx)
                bool gt_p_i = (vp > vi) || (vp == vi && ip < ii);
                bool doswap = ((i & k) == 0) ? gt_p_i : !gt_p_i;
                if (doswap) {
                    sv[i] = vp; sv[pr] = vi;
                    si[i] = (u16)ip; si[pr] = (u16)ii;
                }
            }
        }
    }
    __syncthreads();
    // x_pool rows for this graph (f32)
    for (int t = tid; t < KOUT * 128; t += 1024) {
        int rr = t >> 7, cc = t & 127;
        int node = g * NPG + (int)si[rr];
        float val = sv[rr];
        out[((size_t)g * KOUT + rr) * 128 + cc] = h[(size_t)node * 128 + cc] * val;
    }
    // batch_pool (f32 values matching int ref numerically)
    for (int t = tid; t < KOUT; t += 1024)
        out[(size_t)4 * KOUT * 128 + (size_t)g * KOUT + t] = (float)g;
}

extern "C" void kernel_launch(void* const* d_in, const int* in_sizes, int n_in,
                              void* d_out, int out_size, void* d_ws, size_t ws_size,
                              hipStream_t stream) {
    const float* x        = (const float*)d_in[0];
    const float* mesh_pos = (const float*)d_in[1];
    const int*   edges    = (const int*)d_in[2];
    // d_in[3] = batch_idx (unused; batch = node >> 13)
    const float* proj_w   = (const float*)d_in[4];
    const float* proj_b   = (const float*)d_in[5];
    const float* msg_w1   = (const float*)d_in[6];
    const float* msg_b1   = (const float*)d_in[7];
    const float* msg_w2   = (const float*)d_in[8];
    const float* msg_b2   = (const float*)d_in[9];
    const float* upd_w1   = (const float*)d_in[10];
    const float* upd_b1   = (const float*)d_in[11];
    const float* upd_w2   = (const float*)d_in[12];
    const float* upd_b2   = (const float*)d_in[13];
    const float* pool_rel_w  = (const float*)d_in[14];
    const float* pool_rel_b  = (const float*)d_in[15];
    const float* pool_root_w = (const float*)d_in[16];
    float* out = (float*)d_out;   // reference output dtype is float32

    // workspace layout: 3 x 16MB f32 node buffers + 3MB small arrays = 51MB total
    char* w = (char*)d_ws;
    float* h  = (float*)(w);                   // h0 -> h_new (in place)
    float* v  = (float*)(w + (1ull << 24));    // v -> later agg
    float* S  = (float*)(w + (2ull << 24));    // S -> later q
    char* sm  = w + (3ull << 24);
    int*   deg   = (int*)(sm);
    int*   off   = (int*)(sm + 131072);
    int*   cur   = (int*)(sm + 262144);
    float* rsA   = (float*)(sm + 393216);
    float* bgA   = (float*)(sm + 524288);
    float* pp    = (float*)(sm + 655360);
    float* rr    = (float*)(sm + 786432);
    float* score = (float*)(sm + 917504);
    int*   csr   = (int*)(sm + 1048576);       // 2MB -> ends at 51MB

    k_zero<<<128, 256, 0, stream>>>(deg);
    k_h0<<<N_NODESC / 2, 256, 0, stream>>>(x, mesh_pos, proj_w, proj_b, h);
    k_deg<<<N_EDGESC / 256, 256, 0, stream>>>(edges, deg);
    k_scan<<<1, 1024, 0, stream>>>(deg, off, cur, rsA, bgA);
    k_fill<<<N_EDGESC / 256, 256, 0, stream>>>(edges, cur, csr);

    // v = h@W1b  (src-side message pre-activation)
    gemm128<<<512, 256, 0, stream>>>(h, msg_w1 + 128 * 128, nullptr, nullptr, nullptr,
                                     nullptr, nullptr, nullptr, v, 0);
    // S[d] = sum_e silu( (h[d]@W1a + b1) + v[src_e] )   (u computed in-kernel)
    k_accum_S<<<N_NODESC / 4, 256, 0, stream>>>(h, msg_w1, msg_b1, v, csr, off, deg, S);
    // agg = (S@W2)/cnt + b2*[deg>0]   (into v; v dead after accum)
    gemm128<<<512, 256, 0, stream>>>(S, msg_w2, nullptr, nullptr, msg_b2,
                                     rsA, bgA, nullptr, v, 0);
    // q = silu(h@U1a + agg@U1b + ub1)  (into S; S dead after agg gemm)
    gemm128<<<512, 256, 0, stream>>>(h, upd_w1, v, upd_w1 + 128 * 128, upd_b1,
                                     nullptr, nullptr, nullptr, S, 1);
    // h = h + q@U2 + ub2   (in place)
    gemm128<<<512, 256, 0, stream>>>(S, upd_w2, nullptr, nullptr, upd_b2,
                                     nullptr, nullptr, h, h, 0);

    k_pr<<<N_NODESC / 4, 256, 0, stream>>>(h, pool_rel_w, pool_root_w, pp, rr);
    k_score<<<N_NODESC / 4, 256, 0, stream>>>(pp, rr, csr, off, deg, pool_rel_b, score);
    k_topk<<<4, 1024, 0, stream>>>(score, h, out);
}

// Round 5
// 540.623 us; speedup vs baseline: 1.0944x; 1.0944x over previous
//
#include <hip/hip_runtime.h>
#include <hip/hip_bf16.h>
#include <math.h>

#define N_NODESC 32768
#define N_EDGESC 524288
#define NPG 8192
#define KOUT 512

typedef unsigned short u16;
typedef unsigned int u32;

__device__ __forceinline__ float siluf(float x) {
    return x / (1.f + __expf(-x));
}

// ---------------- zero deg ----------------
__global__ __launch_bounds__(256) void k_zero(int* deg) {
    int i = blockIdx.x * 256 + threadIdx.x;
    if (i < N_NODESC) deg[i] = 0;
}

// ---------------- h0 = x@proj_w + proj_b + sincos(mesh_pos) ----------------
__global__ __launch_bounds__(256) void k_h0(const float* __restrict__ x,
                                            const float* __restrict__ pos,
                                            const float* __restrict__ pw,
                                            const float* __restrict__ pb,
                                            float* __restrict__ h) {
    int node = blockIdx.x * 2 + (threadIdx.x >> 7);
    int c = threadIdx.x & 127;
    float x0 = x[node * 3 + 0];
    float x1 = x[node * 3 + 1];
    float x2 = x[node * 3 + 2];
    float acc = x0 * pw[c] + x1 * pw[128 + c] + x2 * pw[256 + c];
    acc += pb[c];
    int dim = c >> 6;          // which pos coordinate
    int inner = c & 63;        // 0..63 within [sin(32), cos(32)]
    int jj = inner & 31;
    float p = pos[node * 2 + dim];
    // omega_j = 10000^(-j/32) = 2^(-j*log2(10000)/32)
    float omega = exp2f(-(float)jj * 0.41524101186092027f);
    float ang = p * omega;
    acc += (inner < 32) ? __sinf(ang) : __cosf(ang);
    h[(size_t)node * 128 + c] = acc;
}

// ---------------- degree histogram ----------------
__global__ __launch_bounds__(256) void k_deg(const int* __restrict__ edges, int* __restrict__ deg) {
    int e = blockIdx.x * 256 + threadIdx.x;
    if (e < N_EDGESC) {
        int2 e2 = ((const int2*)edges)[e];
        atomicAdd(&deg[e2.y], 1);
    }
}

// ---------------- exclusive scan (32768 = 1024 threads x 32) ----------------
__global__ __launch_bounds__(1024) void k_scan(const int* __restrict__ deg,
                                               int* __restrict__ off, int* __restrict__ cur,
                                               float* __restrict__ rs, float* __restrict__ bg) {
    __shared__ int ls[1024];
    int tid = threadIdx.x;
    int base = tid * 32;
    int v[32];
    int s = 0;
#pragma unroll
    for (int j = 0; j < 32; j++) { v[j] = deg[base + j]; s += v[j]; }
    ls[tid] = s;
    __syncthreads();
    for (int ofs = 1; ofs < 1024; ofs <<= 1) {
        int t = (tid >= ofs) ? ls[tid - ofs] : 0;
        __syncthreads();
        ls[tid] += t;
        __syncthreads();
    }
    int run = ls[tid] - s;  // exclusive prefix for this thread's chunk
#pragma unroll
    for (int j = 0; j < 32; j++) {
        off[base + j] = run;
        cur[base + j] = run;
        int d = v[j];
        rs[base + j] = 1.f / (float)(d > 0 ? d : 1);
        bg[base + j] = d > 0 ? 1.f : 0.f;
        run += d;
    }
}

// ---------------- CSR fill ----------------
__global__ __launch_bounds__(256) void k_fill(const int* __restrict__ edges,
                                              int* __restrict__ cur, int* __restrict__ csr) {
    int e = blockIdx.x * 256 + threadIdx.x;
    if (e < N_EDGESC) {
        int2 e2 = ((const int2*)edges)[e];
        int pos = atomicAdd(&cur[e2.y], 1);
        csr[pos] = e2.x;
    }
}

// ---------------- generic f32 GEMM ----------------
// C = act((A1@W1 [+A2@W2])*rs + bias*bg + resid); optional fused p/r dot-products.
// A: [32768 x 128] f32, W: [128 x 128] f32 row-major. 1024 blocks x 256 thr; 32-row tile; 4x4/thread.
__global__ __launch_bounds__(256) void gemm128(const float* __restrict__ A1, const float* __restrict__ W1,
                                               const float* __restrict__ A2, const float* __restrict__ W2,
                                               const float* __restrict__ bias,
                                               const float* __restrict__ rs, const float* __restrict__ bg,
                                               const float* __restrict__ resid,
                                               float* __restrict__ C, int act,
                                               const float* __restrict__ wrel, const float* __restrict__ wroot,
                                               float* __restrict__ pout, float* __restrict__ rout) {
    int cg = threadIdx.x & 31;   // 32 col groups x 4 cols
    int rg = threadIdx.x >> 5;   // 8 row groups x 4 rows
    int m0 = blockIdx.x * 32 + rg * 4;
    int c0 = cg * 4;
    float acc[4][4];
#pragma unroll
    for (int r = 0; r < 4; r++)
#pragma unroll
        for (int c = 0; c < 4; c++) acc[r][c] = 0.f;

    const float* Arow1 = A1 + (size_t)m0 * 128;
    const float* Arow2 = A2 ? (A2 + (size_t)m0 * 128) : nullptr;

    for (int k0 = 0; k0 < 128; k0 += 4) {
        float4 a1[4];
#pragma unroll
        for (int r = 0; r < 4; r++) a1[r] = *(const float4*)(Arow1 + r * 128 + k0);
#pragma unroll
        for (int kk = 0; kk < 4; kk++) {
            float4 w = *(const float4*)(W1 + (size_t)(k0 + kk) * 128 + c0);
#pragma unroll
            for (int r = 0; r < 4; r++) {
                float a = ((const float*)&a1[r])[kk];
                acc[r][0] += a * w.x;
                acc[r][1] += a * w.y;
                acc[r][2] += a * w.z;
                acc[r][3] += a * w.w;
            }
        }
        if (A2) {
            float4 a2[4];
#pragma unroll
            for (int r = 0; r < 4; r++) a2[r] = *(const float4*)(Arow2 + r * 128 + k0);
#pragma unroll
            for (int kk = 0; kk < 4; kk++) {
                float4 w = *(const float4*)(W2 + (size_t)(k0 + kk) * 128 + c0);
#pragma unroll
                for (int r = 0; r < 4; r++) {
                    float a = ((const float*)&a2[r])[kk];
                    acc[r][0] += a * w.x;
                    acc[r][1] += a * w.y;
                    acc[r][2] += a * w.z;
                    acc[r][3] += a * w.w;
                }
            }
        }
    }

    float prel[4], prot[4];
#pragma unroll
    for (int r = 0; r < 4; r++) {
        int row = m0 + r;
        float rsv = rs ? rs[row] : 1.f;
        float bgv = bg ? bg[row] : 1.f;
        float4 o;
        float* op = (float*)&o;
#pragma unroll
        for (int c = 0; c < 4; c++) {
            float xv = acc[r][c] * rsv;
            if (bias) xv += bias[c0 + c] * bgv;
            if (resid) xv += resid[(size_t)row * 128 + c0 + c];
            if (act) xv = siluf(xv);
            op[c] = xv;
        }
        if (wrel) {
            prel[r] = op[0] * wrel[c0] + op[1] * wrel[c0 + 1] + op[2] * wrel[c0 + 2] + op[3] * wrel[c0 + 3];
            prot[r] = op[0] * wroot[c0] + op[1] * wroot[c0 + 1] + op[2] * wroot[c0 + 2] + op[3] * wroot[c0 + 3];
        }
        *(float4*)(C + (size_t)row * 128 + c0) = o;
    }
    if (wrel) {
#pragma unroll
        for (int r = 0; r < 4; r++) {
            float a = prel[r], b = prot[r];
#pragma unroll
            for (int m = 1; m < 32; m <<= 1) {
                a += __shfl_xor(a, m);
                b += __shfl_xor(b, m);
            }
            if (cg == 0) { pout[m0 + r] = a; rout[m0 + r] = b; }
        }
    }
}

// ---------------- S[d] = sum_{e:dst=d} silu(u[d] + v[src_e]) ; wave per node ----------------
// u[d] is pre-stored IN S by a prior gemm; read it, accumulate, overwrite.
__global__ __launch_bounds__(256) void k_accum_S(const float* __restrict__ v,
                                                 const int* __restrict__ csr, const int* __restrict__ off,
                                                 const int* __restrict__ deg, float* S) {
    int d = blockIdx.x * 4 + (threadIdx.x >> 6);
    int lane = threadIdx.x & 63;
    float* srow = S + (size_t)d * 128;
    float u0 = srow[lane];
    float u1 = srow[64 + lane];
    float a0 = 0.f, a1 = 0.f;
    int o = off[d], n = deg[d];
    for (int base = 0; base < n; base += 64) {
        int cnt = min(64, n - base);
        int sall = (lane < cnt) ? csr[o + base + lane] : 0;  // coalesced chunk of src indices
        int s0 = __shfl(sall, 0);
        float pv0 = v[(size_t)s0 * 128 + lane];
        float pv1 = v[(size_t)s0 * 128 + 64 + lane];
        for (int j = 0; j < cnt; j++) {
            float cv0 = pv0, cv1 = pv1;
            if (j + 1 < cnt) {
                int s1 = __shfl(sall, j + 1);
                pv0 = v[(size_t)s1 * 128 + lane];     // prefetch next edge's row
                pv1 = v[(size_t)s1 * 128 + 64 + lane];
            }
            a0 += siluf(u0 + cv0);
            a1 += siluf(u1 + cv1);
        }
    }
    srow[lane] = a0;
    srow[64 + lane] = a1;
}

// ---------------- score[d] = tanh( (sum p[src]) / cnt + rel_b + r[d] ) ----------------
__global__ __launch_bounds__(256) void k_score(const float* __restrict__ p, const float* __restrict__ r,
                                               const int* __restrict__ csr, const int* __restrict__ off,
                                               const int* __restrict__ deg, const float* __restrict__ relb,
                                               float* __restrict__ score) {
    int d = blockIdx.x * 4 + (threadIdx.x >> 6);
    int lane = threadIdx.x & 63;
    int o = off[d], n = deg[d];
    float a = 0.f;
    for (int j = lane; j < n; j += 64) a += p[csr[o + j]];
    for (int m = 32; m > 0; m >>= 1) a += __shfl_xor(a, m);
    if (lane == 0) {
        float cnt = (float)(n > 0 ? n : 1);
        score[d] = tanhf(a / cnt + relb[0] + r[d]);
    }
}

// ---------------- per-graph bitonic top-k + output write (FLOAT32 out) ----------------
__global__ __launch_bounds__(1024) void k_topk(const float* __restrict__ score, const float* __restrict__ h,
                                               float* __restrict__ out) {
    __shared__ float sv[NPG];
    __shared__ u16 si[NPG];
    int g = blockIdx.x;
    int tid = threadIdx.x;
    for (int i = tid; i < NPG; i += 1024) {
        sv[i] = score[(size_t)g * NPG + i];
        si[i] = (u16)i;
    }
    for (int k = 2; k <= NPG; k <<= 1) {
        for (int j = k >> 1; j > 0; j >>= 1) {
            __syncthreads();
            for (int t = tid; t < NPG / 2; t += 1024) {
                int i = ((t & ~(j - 1)) << 1) | (t & (j - 1));
                int pr = i | j;
                float vi = sv[i], vp = sv[pr];
                int ii = si[i], ip = si[pr];
                // gt(a,b): a ranks before b in final order (desc value, tie -> lower idx)
                bool gt_p_i = (vp > vi) || (vp == vi && ip < ii);
                bool doswap = ((i & k) == 0) ? gt_p_i : !gt_p_i;
                if (doswap) {
                    sv[i] = vp; sv[pr] = vi;
                    si[i] = (u16)ip; si[pr] = (u16)ii;
                }
            }
        }
    }
    __syncthreads();
    // x_pool rows for this graph (f32)
    for (int t = tid; t < KOUT * 128; t += 1024) {
        int rr = t >> 7, cc = t & 127;
        int node = g * NPG + (int)si[rr];
        float val = sv[rr];
        out[((size_t)g * KOUT + rr) * 128 + cc] = h[(size_t)node * 128 + cc] * val;
    }
    // batch_pool (f32 values matching int ref numerically)
    for (int t = tid; t < KOUT; t += 1024)
        out[(size_t)4 * KOUT * 128 + (size_t)g * KOUT + t] = (float)g;
}

extern "C" void kernel_launch(void* const* d_in, const int* in_sizes, int n_in,
                              void* d_out, int out_size, void* d_ws, size_t ws_size,
                              hipStream_t stream) {
    const float* x        = (const float*)d_in[0];
    const float* mesh_pos = (const float*)d_in[1];
    const int*   edges    = (const int*)d_in[2];
    // d_in[3] = batch_idx (unused; batch = node >> 13)
    const float* proj_w   = (const float*)d_in[4];
    const float* proj_b   = (const float*)d_in[5];
    const float* msg_w1   = (const float*)d_in[6];
    const float* msg_b1   = (const float*)d_in[7];
    const float* msg_w2   = (const float*)d_in[8];
    const float* msg_b2   = (const float*)d_in[9];
    const float* upd_w1   = (const float*)d_in[10];
    const float* upd_b1   = (const float*)d_in[11];
    const float* upd_w2   = (const float*)d_in[12];
    const float* upd_b2   = (const float*)d_in[13];
    const float* pool_rel_w  = (const float*)d_in[14];
    const float* pool_rel_b  = (const float*)d_in[15];
    const float* pool_root_w = (const float*)d_in[16];
    float* out = (float*)d_out;   // reference output dtype is float32

    // workspace layout: 3 x 16MB f32 node buffers + 3MB small arrays = 51MB total
    char* w = (char*)d_ws;
    float* h  = (float*)(w);                   // h0 -> h_new (in place)
    float* v  = (float*)(w + (1ull << 24));    // v -> later agg
    float* S  = (float*)(w + (2ull << 24));    // u -> S -> later q
    char* sm  = w + (3ull << 24);
    int*   deg   = (int*)(sm);
    int*   off   = (int*)(sm + 131072);
    int*   cur   = (int*)(sm + 262144);
    float* rsA   = (float*)(sm + 393216);
    float* bgA   = (float*)(sm + 524288);
    float* pp    = (float*)(sm + 655360);
    float* rr    = (float*)(sm + 786432);
    float* score = (float*)(sm + 917504);
    int*   csr   = (int*)(sm + 1048576);       // 2MB -> ends at 51MB

    k_zero<<<128, 256, 0, stream>>>(deg);
    k_h0<<<N_NODESC / 2, 256, 0, stream>>>(x, mesh_pos, proj_w, proj_b, h);
    k_deg<<<N_EDGESC / 256, 256, 0, stream>>>(edges, deg);
    k_scan<<<1, 1024, 0, stream>>>(deg, off, cur, rsA, bgA);
    k_fill<<<N_EDGESC / 256, 256, 0, stream>>>(edges, cur, csr);

    // v = h@W1b  (src-side message pre-activation)
    gemm128<<<1024, 256, 0, stream>>>(h, msg_w1 + 128 * 128, nullptr, nullptr, nullptr,
                                      nullptr, nullptr, nullptr, v, 0,
                                      nullptr, nullptr, nullptr, nullptr);
    // u = h@W1a + b1  (into S; k_accum_S reads it back from S)
    gemm128<<<1024, 256, 0, stream>>>(h, msg_w1, nullptr, nullptr, msg_b1,
                                      nullptr, nullptr, nullptr, S, 0,
                                      nullptr, nullptr, nullptr, nullptr);
    // S[d] = sum_e silu( u[d] + v[src_e] )   (in place on S)
    k_accum_S<<<N_NODESC / 4, 256, 0, stream>>>(v, csr, off, deg, S);
    // agg = (S@W2)/cnt + b2*[deg>0]   (into v; v dead after accum)
    gemm128<<<1024, 256, 0, stream>>>(S, msg_w2, nullptr, nullptr, msg_b2,
                                      rsA, bgA, nullptr, v, 0,
                                      nullptr, nullptr, nullptr, nullptr);
    // q = silu(h@U1a + agg@U1b + ub1)  (into S; S dead after agg gemm)
    gemm128<<<1024, 256, 0, stream>>>(h, upd_w1, v, upd_w1 + 128 * 128, upd_b1,
                                      nullptr, nullptr, nullptr, S, 1,
                                      nullptr, nullptr, nullptr, nullptr);
    // h = h + q@U2 + ub2   (in place) + fused p,r dot-products
    gemm128<<<1024, 256, 0, stream>>>(S, upd_w2, nullptr, nullptr, upd_b2,
                                      nullptr, nullptr, h, h, 0,
                                      pool_rel_w, pool_root_w, pp, rr);

    k_score<<<N_NODESC / 4, 256, 0, stream>>>(pp, rr, csr, off, deg, pool_rel_b, score);
    k_topk<<<4, 1024, 0, stream>>>(score, h, out);
}

// Round 6
// 451.036 us; speedup vs baseline: 1.3118x; 1.1986x over previous
//
#include <hip/hip_runtime.h>
#include <hip/hip_bf16.h>
#include <math.h>

#define N_NODESC 32768
#define N_EDGESC 524288
#define NPG 8192
#define KOUT 512

typedef unsigned short u16;
typedef unsigned int u32;
typedef unsigned long long u64;

__device__ __forceinline__ float siluf(float x) {
    return x / (1.f + __expf(-x));
}

// ---------------- h0 = x@proj_w + proj_b + sincos(mesh_pos)  (+ zero deg) ----------------
__global__ __launch_bounds__(256) void k_h0(const float* __restrict__ x,
                                            const float* __restrict__ pos,
                                            const float* __restrict__ pw,
                                            const float* __restrict__ pb,
                                            float* __restrict__ h,
                                            int* __restrict__ deg) {
    int gid = blockIdx.x * 256 + threadIdx.x;
    if (gid < N_NODESC) deg[gid] = 0;
    int node = blockIdx.x * 2 + (threadIdx.x >> 7);
    int c = threadIdx.x & 127;
    float x0 = x[node * 3 + 0];
    float x1 = x[node * 3 + 1];
    float x2 = x[node * 3 + 2];
    float acc = x0 * pw[c] + x1 * pw[128 + c] + x2 * pw[256 + c];
    acc += pb[c];
    int dim = c >> 6;          // which pos coordinate
    int inner = c & 63;        // 0..63 within [sin(32), cos(32)]
    int jj = inner & 31;
    float p = pos[node * 2 + dim];
    // omega_j = 10000^(-j/32) = 2^(-j*log2(10000)/32)
    float omega = exp2f(-(float)jj * 0.41524101186092027f);
    float ang = p * omega;
    acc += (inner < 32) ? __sinf(ang) : __cosf(ang);
    h[(size_t)node * 128 + c] = acc;
}

// ---------------- degree histogram ----------------
__global__ __launch_bounds__(256) void k_deg(const int* __restrict__ edges, int* __restrict__ deg) {
    int e = blockIdx.x * 256 + threadIdx.x;
    if (e < N_EDGESC) {
        int2 e2 = ((const int2*)edges)[e];
        atomicAdd(&deg[e2.y], 1);
    }
}

// ---------------- exclusive scan (32768 = 1024 threads x 32) ----------------
__global__ __launch_bounds__(1024) void k_scan(const int* __restrict__ deg,
                                               int* __restrict__ off, int* __restrict__ cur,
                                               float* __restrict__ rs, float* __restrict__ bg) {
    __shared__ int ls[1024];
    int tid = threadIdx.x;
    int base = tid * 32;
    int v[32];
    int s = 0;
#pragma unroll
    for (int j = 0; j < 32; j++) { v[j] = deg[base + j]; s += v[j]; }
    ls[tid] = s;
    __syncthreads();
    for (int ofs = 1; ofs < 1024; ofs <<= 1) {
        int t = (tid >= ofs) ? ls[tid - ofs] : 0;
        __syncthreads();
        ls[tid] += t;
        __syncthreads();
    }
    int run = ls[tid] - s;  // exclusive prefix for this thread's chunk
#pragma unroll
    for (int j = 0; j < 32; j++) {
        off[base + j] = run;
        cur[base + j] = run;
        int d = v[j];
        rs[base + j] = 1.f / (float)(d > 0 ? d : 1);
        bg[base + j] = d > 0 ? 1.f : 0.f;
        run += d;
    }
}

// ---------------- CSR fill ----------------
__global__ __launch_bounds__(256) void k_fill(const int* __restrict__ edges,
                                              int* __restrict__ cur, int* __restrict__ csr) {
    int e = blockIdx.x * 256 + threadIdx.x;
    if (e < N_EDGESC) {
        int2 e2 = ((const int2*)edges)[e];
        int pos = atomicAdd(&cur[e2.y], 1);
        csr[pos] = e2.x;
    }
}

// ---------------- dual GEMM: V = A@Wv ; U = A@Wu + bu ---------------
// one pass over A, two accumulators. 1024 blocks x 256 thr; 32-row tile; 4x4x2/thread.
__global__ __launch_bounds__(256) void gemm_dual(const float* __restrict__ A,
                                                 const float* __restrict__ Wv,
                                                 const float* __restrict__ Wu,
                                                 const float* __restrict__ bu,
                                                 float* __restrict__ V, float* __restrict__ U) {
    int cg = threadIdx.x & 31;
    int rg = threadIdx.x >> 5;
    int m0 = blockIdx.x * 32 + rg * 4;
    int c0 = cg * 4;
    float av[4][4], au[4][4];
#pragma unroll
    for (int r = 0; r < 4; r++)
#pragma unroll
        for (int c = 0; c < 4; c++) { av[r][c] = 0.f; au[r][c] = 0.f; }

    const float* Arow = A + (size_t)m0 * 128;
    for (int k0 = 0; k0 < 128; k0 += 4) {
        float4 a[4];
#pragma unroll
        for (int r = 0; r < 4; r++) a[r] = *(const float4*)(Arow + r * 128 + k0);
#pragma unroll
        for (int kk = 0; kk < 4; kk++) {
            float4 wv = *(const float4*)(Wv + (size_t)(k0 + kk) * 128 + c0);
            float4 wu = *(const float4*)(Wu + (size_t)(k0 + kk) * 128 + c0);
#pragma unroll
            for (int r = 0; r < 4; r++) {
                float aa = ((const float*)&a[r])[kk];
                av[r][0] += aa * wv.x; av[r][1] += aa * wv.y; av[r][2] += aa * wv.z; av[r][3] += aa * wv.w;
                au[r][0] += aa * wu.x; au[r][1] += aa * wu.y; au[r][2] += aa * wu.z; au[r][3] += aa * wu.w;
            }
        }
    }
#pragma unroll
    for (int r = 0; r < 4; r++) {
        int row = m0 + r;
        float4 ov, ou;
        ov.x = av[r][0]; ov.y = av[r][1]; ov.z = av[r][2]; ov.w = av[r][3];
        ou.x = au[r][0] + bu[c0]; ou.y = au[r][1] + bu[c0 + 1];
        ou.z = au[r][2] + bu[c0 + 2]; ou.w = au[r][3] + bu[c0 + 3];
        *(float4*)(V + (size_t)row * 128 + c0) = ov;
        *(float4*)(U + (size_t)row * 128 + c0) = ou;
    }
}

// ---------------- generic f32 GEMM ----------------
// C = act((A1@W1 [+A2@W2])*rs + bias*bg + resid); optional fused p/r dot-products.
__global__ __launch_bounds__(256) void gemm128(const float* __restrict__ A1, const float* __restrict__ W1,
                                               const float* __restrict__ A2, const float* __restrict__ W2,
                                               const float* __restrict__ bias,
                                               const float* __restrict__ rs, const float* __restrict__ bg,
                                               const float* __restrict__ resid,
                                               float* __restrict__ C, int act,
                                               const float* __restrict__ wrel, const float* __restrict__ wroot,
                                               float* __restrict__ pout, float* __restrict__ rout) {
    int cg = threadIdx.x & 31;   // 32 col groups x 4 cols
    int rg = threadIdx.x >> 5;   // 8 row groups x 4 rows
    int m0 = blockIdx.x * 32 + rg * 4;
    int c0 = cg * 4;
    float acc[4][4];
#pragma unroll
    for (int r = 0; r < 4; r++)
#pragma unroll
        for (int c = 0; c < 4; c++) acc[r][c] = 0.f;

    const float* Arow1 = A1 + (size_t)m0 * 128;
    const float* Arow2 = A2 ? (A2 + (size_t)m0 * 128) : nullptr;

    for (int k0 = 0; k0 < 128; k0 += 4) {
        float4 a1[4];
#pragma unroll
        for (int r = 0; r < 4; r++) a1[r] = *(const float4*)(Arow1 + r * 128 + k0);
#pragma unroll
        for (int kk = 0; kk < 4; kk++) {
            float4 w = *(const float4*)(W1 + (size_t)(k0 + kk) * 128 + c0);
#pragma unroll
            for (int r = 0; r < 4; r++) {
                float a = ((const float*)&a1[r])[kk];
                acc[r][0] += a * w.x;
                acc[r][1] += a * w.y;
                acc[r][2] += a * w.z;
                acc[r][3] += a * w.w;
            }
        }
        if (A2) {
            float4 a2[4];
#pragma unroll
            for (int r = 0; r < 4; r++) a2[r] = *(const float4*)(Arow2 + r * 128 + k0);
#pragma unroll
            for (int kk = 0; kk < 4; kk++) {
                float4 w = *(const float4*)(W2 + (size_t)(k0 + kk) * 128 + c0);
#pragma unroll
                for (int r = 0; r < 4; r++) {
                    float a = ((const float*)&a2[r])[kk];
                    acc[r][0] += a * w.x;
                    acc[r][1] += a * w.y;
                    acc[r][2] += a * w.z;
                    acc[r][3] += a * w.w;
                }
            }
        }
    }

    float prel[4], prot[4];
#pragma unroll
    for (int r = 0; r < 4; r++) {
        int row = m0 + r;
        float rsv = rs ? rs[row] : 1.f;
        float bgv = bg ? bg[row] : 1.f;
        float4 o;
        float* op = (float*)&o;
#pragma unroll
        for (int c = 0; c < 4; c++) {
            float xv = acc[r][c] * rsv;
            if (bias) xv += bias[c0 + c] * bgv;
            if (resid) xv += resid[(size_t)row * 128 + c0 + c];
            if (act) xv = siluf(xv);
            op[c] = xv;
        }
        if (wrel) {
            prel[r] = op[0] * wrel[c0] + op[1] * wrel[c0 + 1] + op[2] * wrel[c0 + 2] + op[3] * wrel[c0 + 3];
            prot[r] = op[0] * wroot[c0] + op[1] * wroot[c0 + 1] + op[2] * wroot[c0 + 2] + op[3] * wroot[c0 + 3];
        }
        *(float4*)(C + (size_t)row * 128 + c0) = o;
    }
    if (wrel) {
#pragma unroll
        for (int r = 0; r < 4; r++) {
            float a = prel[r], b = prot[r];
#pragma unroll
            for (int m = 1; m < 32; m <<= 1) {
                a += __shfl_xor(a, m);
                b += __shfl_xor(b, m);
            }
            if (cg == 0) { pout[m0 + r] = a; rout[m0 + r] = b; }
        }
    }
}

// ---------------- S[d] = sum_{e:dst=d} silu(u[d] + v[src_e]) ; wave per node ----------------
// u[d] is pre-stored IN S; read it, accumulate, overwrite. Depth-2 prefetch on v rows.
__global__ __launch_bounds__(256) void k_accum_S(const float* __restrict__ v,
                                                 const int* __restrict__ csr, const int* __restrict__ off,
                                                 const int* __restrict__ deg, float* S) {
    int d = blockIdx.x * 4 + (threadIdx.x >> 6);
    int lane = threadIdx.x & 63;
    float* srow = S + (size_t)d * 128;
    float u0 = srow[lane];
    float u1 = srow[64 + lane];
    float a0 = 0.f, a1 = 0.f;
    int o = off[d], n = deg[d];
    for (int base = 0; base < n; base += 64) {
        int cnt = min(64, n - base);
        int sall = (lane < cnt) ? csr[o + base + lane] : 0;  // coalesced chunk of src indices
        int s0 = __shfl(sall, 0);
        float p00 = v[(size_t)s0 * 128 + lane];
        float p01 = v[(size_t)s0 * 128 + 64 + lane];
        float p10 = 0.f, p11 = 0.f;
        if (cnt > 1) {
            int s1 = __shfl(sall, 1);
            p10 = v[(size_t)s1 * 128 + lane];
            p11 = v[(size_t)s1 * 128 + 64 + lane];
        }
        for (int j = 0; j < cnt; j++) {
            float cv0 = p00, cv1 = p01;
            p00 = p10; p01 = p11;
            if (j + 2 < cnt) {
                int sn = __shfl(sall, j + 2);
                p10 = v[(size_t)sn * 128 + lane];     // prefetch 2 ahead
                p11 = v[(size_t)sn * 128 + 64 + lane];
            }
            a0 += siluf(u0 + cv0);
            a1 += siluf(u1 + cv1);
        }
    }
    srow[lane] = a0;
    srow[64 + lane] = a1;
}

// ---------------- score[d] = tanh( (sum p[src]) / cnt + rel_b + r[d] ) ----------------
__global__ __launch_bounds__(256) void k_score(const float* __restrict__ p, const float* __restrict__ r,
                                               const int* __restrict__ csr, const int* __restrict__ off,
                                               const int* __restrict__ deg, const float* __restrict__ relb,
                                               float* __restrict__ score) {
    int d = blockIdx.x * 4 + (threadIdx.x >> 6);
    int lane = threadIdx.x & 63;
    int o = off[d], n = deg[d];
    float a = 0.f;
    for (int j = lane; j < n; j += 64) a += p[csr[o + j]];
    for (int m = 32; m > 0; m >>= 1) a += __shfl_xor(a, m);
    if (lane == 0) {
        float cnt = (float)(n > 0 ? n : 1);
        score[d] = tanhf(a / cnt + relb[0] + r[d]);
    }
}

// ---------------- per-graph exact top-k via radix-select + direct ranking ----------------
// Selection/order = sort by (score desc, index asc) == jax.lax.top_k.
__global__ __launch_bounds__(1024) void k_topk(const float* __restrict__ score, const float* __restrict__ h,
                                               float* __restrict__ out) {
    __shared__ u32 ms[NPG];        // 32KB order-preserving mapped scores
    __shared__ u32 hist[256];
    __shared__ u32 sbuf[1024];
    __shared__ u64 sel[KOUT];      // (ms<<32)|(NPG-1-idx); bigger = better rank
    __shared__ float ordv[KOUT];
    __shared__ int ordi[KOUT];
    __shared__ u32 selCnt, sPrefix, sNeed, sB;

    int g = blockIdx.x;
    int tid = threadIdx.x;

    // 1. load + order-preserving map (float -> u32, monotone)
    for (int i = tid; i < NPG; i += 1024) {
        u32 u = __float_as_uint(score[(size_t)g * NPG + i]);
        ms[i] = (u & 0x80000000u) ? ~u : (u | 0x80000000u);
    }
    if (tid == 0) { sNeed = KOUT; sPrefix = 0; selCnt = 0; }
    __syncthreads();

    // 2. four 8-bit MSB->LSB histogram passes -> exact threshold T and tie count
    for (int pass = 0; pass < 4; pass++) {
        int shift = 24 - pass * 8;
        if (tid < 256) hist[tid] = 0;
        __syncthreads();
        u32 pfx = sPrefix;
        for (int i = tid; i < NPG; i += 1024) {
            u32 v = ms[i];
            if (pass == 0 || (v >> (shift + 8)) == pfx)
                atomicAdd(&hist[(v >> shift) & 255u], 1u);
        }
        __syncthreads();
        if (tid < 256) sbuf[tid] = hist[tid];
        __syncthreads();
        // suffix sums: sbuf[b] = sum_{j>=b} hist[j]
        for (int ofs = 1; ofs < 256; ofs <<= 1) {
            u32 t = 0;
            if (tid < 256 && tid + ofs < 256) t = sbuf[tid + ofs];
            __syncthreads();
            if (tid < 256) sbuf[tid] += t;
            __syncthreads();
        }
        u32 need = sNeed;
        if (tid < 256) {
            if (sbuf[tid] >= need && (tid == 255 || sbuf[tid + 1] < need)) sB = (u32)tid;
        }
        __syncthreads();
        if (tid == 0) {
            u32 B = sB;
            u32 above = (B == 255) ? 0u : sbuf[B + 1];
            sNeed = need - above;
            sPrefix = (sPrefix << 8) | B;
        }
        __syncthreads();
    }
    u32 T = sPrefix;     // exact 512th-value (mapped)
    u32 rTie = sNeed;    // how many ==T to take, by smallest index

    // 3. index-ordered rank among ties: each thread owns 8 consecutive indices
    int base = tid * 8;
    u32 lc = 0;
#pragma unroll
    for (int j = 0; j < 8; j++) lc += (ms[base + j] == T);
    __syncthreads();      // protect sbuf (was used for suffix sums)
    sbuf[tid] = lc;
    __syncthreads();
    u32 own = lc;
    for (int ofs = 1; ofs < 1024; ofs <<= 1) {
        u32 t = (tid >= ofs) ? sbuf[tid - ofs] : 0;
        __syncthreads();
        sbuf[tid] += t;
        __syncthreads();
    }
    u32 excl = sbuf[tid] - own;   // ties before my chunk

    // 4. select & compact exactly 512 keys
#pragma unroll
    for (int j = 0; j < 8; j++) {
        int i = base + j;
        u32 v = ms[i];
        bool pick = (v > T) || ((v == T) && (excl < rTie));
        if (v == T) excl++;
        if (pick) {
            u32 slot = atomicAdd(&selCnt, 1u);
            sel[slot] = ((u64)v << 32) | (u32)(NPG - 1 - i);
        }
    }
    __syncthreads();

    // 5. direct rank: 512 threads x 512 broadcast compares (unique keys -> permutation)
    if (tid < KOUT) {
        u64 mine = sel[tid];
        int rank = 0;
        for (int j = 0; j < KOUT; j++) rank += (sel[j] > mine);
        u32 v = (u32)(mine >> 32);
        int idx = NPG - 1 - (int)(mine & 0xFFFFFFFFu);
        u32 uu = (v & 0x80000000u) ? (v & 0x7FFFFFFFu) : ~v;   // unmap
        ordv[rank] = __uint_as_float(uu);
        ordi[rank] = idx;
    }
    __syncthreads();

    // 6. write output
    for (int t = tid; t < KOUT * 128; t += 1024) {
        int r = t >> 7, c = t & 127;
        int node = g * NPG + ordi[r];
        out[((size_t)g * KOUT + r) * 128 + c] = h[(size_t)node * 128 + c] * ordv[r];
    }
    for (int t = tid; t < KOUT; t += 1024)
        out[(size_t)4 * KOUT * 128 + (size_t)g * KOUT + t] = (float)g;
}

extern "C" void kernel_launch(void* const* d_in, const int* in_sizes, int n_in,
                              void* d_out, int out_size, void* d_ws, size_t ws_size,
                              hipStream_t stream) {
    const float* x        = (const float*)d_in[0];
    const float* mesh_pos = (const float*)d_in[1];
    const int*   edges    = (const int*)d_in[2];
    // d_in[3] = batch_idx (unused; batch = node >> 13)
    const float* proj_w   = (const float*)d_in[4];
    const float* proj_b   = (const float*)d_in[5];
    const float* msg_w1   = (const float*)d_in[6];
    const float* msg_b1   = (const float*)d_in[7];
    const float* msg_w2   = (const float*)d_in[8];
    const float* msg_b2   = (const float*)d_in[9];
    const float* upd_w1   = (const float*)d_in[10];
    const float* upd_b1   = (const float*)d_in[11];
    const float* upd_w2   = (const float*)d_in[12];
    const float* upd_b2   = (const float*)d_in[13];
    const float* pool_rel_w  = (const float*)d_in[14];
    const float* pool_rel_b  = (const float*)d_in[15];
    const float* pool_root_w = (const float*)d_in[16];
    float* out = (float*)d_out;   // reference output dtype is float32

    // workspace layout: 3 x 16MB f32 node buffers + 3MB small arrays = 51MB total
    char* w = (char*)d_ws;
    float* h  = (float*)(w);                   // h0 -> h_new (in place)
    float* v  = (float*)(w + (1ull << 24));    // v -> later agg
    float* S  = (float*)(w + (2ull << 24));    // u -> S -> later q
    char* sm  = w + (3ull << 24);
    int*   deg   = (int*)(sm);
    int*   off   = (int*)(sm + 131072);
    int*   cur   = (int*)(sm + 262144);
    float* rsA   = (float*)(sm + 393216);
    float* bgA   = (float*)(sm + 524288);
    float* pp    = (float*)(sm + 655360);
    float* rr    = (float*)(sm + 786432);
    float* score = (float*)(sm + 917504);
    int*   csr   = (int*)(sm + 1048576);       // 2MB -> ends at 51MB

    k_h0<<<N_NODESC / 2, 256, 0, stream>>>(x, mesh_pos, proj_w, proj_b, h, deg);
    k_deg<<<N_EDGESC / 256, 256, 0, stream>>>(edges, deg);
    k_scan<<<1, 1024, 0, stream>>>(deg, off, cur, rsA, bgA);
    k_fill<<<N_EDGESC / 256, 256, 0, stream>>>(edges, cur, csr);

    // v = h@W1b ; u = h@W1a + b1 (into S) — one pass over h
    gemm_dual<<<1024, 256, 0, stream>>>(h, msg_w1 + 128 * 128, msg_w1, msg_b1, v, S);
    // S[d] = sum_e silu( u[d] + v[src_e] )   (in place on S)
    k_accum_S<<<N_NODESC / 4, 256, 0, stream>>>(v, csr, off, deg, S);
    // agg = (S@W2)/cnt + b2*[deg>0]   (into v; v dead after accum)
    gemm128<<<1024, 256, 0, stream>>>(S, msg_w2, nullptr, nullptr, msg_b2,
                                      rsA, bgA, nullptr, v, 0,
                                      nullptr, nullptr, nullptr, nullptr);
    // q = silu(h@U1a + agg@U1b + ub1)  (into S; S dead after agg gemm)
    gemm128<<<1024, 256, 0, stream>>>(h, upd_w1, v, upd_w1 + 128 * 128, upd_b1,
                                      nullptr, nullptr, nullptr, S, 1,
                                      nullptr, nullptr, nullptr, nullptr);
    // h = h + q@U2 + ub2   (in place) + fused p,r dot-products
    gemm128<<<1024, 256, 0, stream>>>(S, upd_w2, nullptr, nullptr, upd_b2,
                                      nullptr, nullptr, h, h, 0,
                                      pool_rel_w, pool_root_w, pp, rr);

    k_score<<<N_NODESC / 4, 256, 0, stream>>>(pp, rr, csr, off, deg, pool_rel_b, score);
    k_topk<<<4, 1024, 0, stream>>>(score, h, out);
}